// Round 3
// baseline (1445.855 us; speedup 1.0000x reference)
//
#include <hip/hip_runtime.h>

// Net_4544075399853: x->20 linear, LSTMCell(20,20), 20->1 linear; B=8192, T=2048, fp32.
// R9b: dual-stream waves (per-stream math bit-identical to R8). R9 failed on a
// preprocessor bug only (F##S##0.x -> "FA" pasted against pp-number "0.x");
// EPILOG now takes fragments as explicit args. Logic unchanged:
//  - Each wave owns 6 batch rows as TWO independent 3-row streams (A,B) with
//    separate LDS h-buffers and c/F/x state, SHARED whh2/u/v (80 weight VGPRs
//    amortized over 2x rows). Bodies alternate A,B,A,B...: each stream's
//    ds_write -> 5x ds_read_b128 round-trip (~150cy) is hidden under the OTHER
//    stream's ~190cy of compute, in program order. This fixes the phase-locked
//    stall: co-resident waves run identical code at identical rates, so wave-level
//    TLP cannot cover the per-step LDS window (VALUBusy was stuck at 76%).
//  - Grid halves to 1366 single-wave blocks (1.33 waves/SIMD) but streams/SIMD
//    stays 2.67 -> same total VALU work, now issued back-to-back.
//  - waves_per_eu(2,2): 256-reg cap (state ~200 VGPRs); 2 waves/SIMD is all the
//    grid can populate anyway.
//  - Barrier-free single-buffer LDS per stream; x as float4 per 4 steps,
//    prefetched one iteration ahead; outputs packed float4 per 4 steps.
//  - Lanes 0-59: 3 rows x 20 units; lanes 60-62: output lanes (whh row0=W2,
//    v[0]=b2) -> their g0 IS out[t-1]. exp2-domain activations.

#define HID 20
#define ROWS_PER_STREAM 3
#define ROWS_PER_BLOCK 6
#define NTHREADS 64
#define L2E 1.4426950408889634f

typedef float v2f __attribute__((ext_vector_type(2)));

__device__ __forceinline__ float exp2_hw(float v) { return __builtin_amdgcn_exp2f(v); }
__device__ __forceinline__ float rcp_hw(float v)  { return __builtin_amdgcn_rcpf(v); }

// gs = log2e * g   -> sigmoid(g)
__device__ __forceinline__ float sig_s(float gs) {
    return rcp_hw(1.0f + exp2_hw(-gs));
}
// gs2 = 2*log2e*g  -> 2*log2e * tanh(g)  (pre-scaled for the c update)
__device__ __forceinline__ float tanh_2Ls(float gs2) {
    return (2.0f * L2E) - (4.0f * L2E) * rcp_hw(1.0f + exp2_hw(gs2));
}
// cs = 2*log2e*c   -> tanh(c)
__device__ __forceinline__ float tanh_c(float cs) {
    return 1.0f - 2.0f * rcp_hw(1.0f + exp2_hw(cs));
}

__global__ __attribute__((amdgpu_flat_work_group_size(NTHREADS, NTHREADS),
                          amdgpu_waves_per_eu(2, 2)))
void lstm_wave(
        const float* __restrict__ x,     // [B, T]
        const float* __restrict__ W1,    // [20]
        const float* __restrict__ b1,    // [20]
        const float* __restrict__ W_ih,  // [80, 20]
        const float* __restrict__ W_hh,  // [80, 20]
        const float* __restrict__ b_ih,  // [80]
        const float* __restrict__ b_hh,  // [80]
        const float* __restrict__ W2,    // [20]
        const float* __restrict__ b2,    // [1]
        float* __restrict__ out,         // [B, T]
        const int B, const int T)
{
    const int lane = threadIdx.x;
    const int lrow = lane / HID;          // 0..3 (3 = special lanes 60-63)
    const int m    = lane % HID;          // 0..19 (0..3 for lanes 60-63)
    const bool outlane = (lrow == 3) && (m < ROWS_PER_STREAM);   // lanes 60,61,62
    const int rslot = (lrow == 3) ? m : lrow;  // LDS row slot this lane READS (<=3)
    const long rowbase = (long)blockIdx.x * ROWS_PER_BLOCK;
    const long rowA = rowbase + ((lrow == 3) ? (long)((m < 3) ? m : 0) : (long)lrow);
    const long rowB = rowA + ROWS_PER_STREAM;
    const long arowA = (rowA < B) ? rowA : (B - 1);  // safe address for OOB/aux lanes
    const long arowB = (rowB < B) ? rowB : (B - 1);
    const bool ovalidA = outlane && (rowA < B);
    const bool ovalidB = outlane && (rowB < B);

    // per-stream single buffer: [stream][4 row slots (slot 3 = trash)][20 units]
    __shared__ __align__(16) float hbuf[2][ROWS_PER_STREAM + 1][HID];

    // ---- phase 1: u, v (NO weight arrays live here; W1/b1 are uniform loads) ----
    float u[4], v[4];
    if (lrow < 3) {
#pragma unroll
        for (int g = 0; g < 4; ++g) {
            const int j = g * HID + m;            // torch gate order i,f,g,o
            const float s = (g == 2) ? (2.0f * L2E) : L2E;
            float uu = 0.f, vv = 0.f;
#pragma unroll
            for (int k = 0; k < HID; ++k) {
                const float wi = W_ih[j * HID + k];
                uu += wi * W1[k];
                vv += wi * b1[k];
            }
            u[g] = s * uu;
            v[g] = s * (vv + b_ih[j] + b_hh[j]);
        }
    } else {
#pragma unroll
        for (int g = 0; g < 4; ++g) { u[g] = 0.f; v[g] = 0.f; }
        v[0] = b2[0];
    }

    // ---- phase 2: whh as 40 float2 pairs (scaled), loaded with low live-set ----
    v2f whh2[4][HID / 2];
    if (lrow < 3) {
#pragma unroll
        for (int g = 0; g < 4; ++g) {
            const int j = g * HID + m;
            const float s = (g == 2) ? (2.0f * L2E) : L2E;
#pragma unroll
            for (int kk = 0; kk < HID / 2; ++kk) {
                v2f w;
                w.x = s * W_hh[j * HID + 2 * kk];
                w.y = s * W_hh[j * HID + 2 * kk + 1];
                whh2[g][kk] = w;
            }
        }
    } else {
#pragma unroll
        for (int kk = 0; kk < HID / 2; ++kk) {
            v2f w; w.x = W2[2 * kk]; w.y = W2[2 * kk + 1];
            whh2[0][kk] = w;
            whh2[1][kk] = (v2f)(0.f);
            whh2[2][kk] = (v2f)(0.f);
            whh2[3][kk] = (v2f)(0.f);
        }
    }

    // Opaque defs: prevent remat of the weight loads into the loop.
#pragma unroll
    for (int g = 0; g < 4; ++g)
#pragma unroll
        for (int kk = 0; kk < HID / 2; ++kk)
            asm volatile("" : "+v"(whh2[g][kk]));

    float csA = 0.f, csB = 0.f;   // c in 2*log2e-scaled domain
    hbuf[0][lrow][m] = 0.f;
    hbuf[1][lrow][m] = 0.f;
    if (lane < HID) { hbuf[0][3][lane] = 0.f; hbuf[1][3][lane] = 0.f; }
    // NOTE: no __syncthreads anywhere — single-wave workgroup, DS ops are
    // executed in wave program order by the LDS pipe.

    const float* __restrict__ xrowA = x   + arowA * T;
    const float* __restrict__ xrowB = x   + arowB * T;
    float* __restrict__       orowA = out + arowA * T;
    float* __restrict__       orowB = out + arowB * T;

    const float4* __restrict__ rdpA = (const float4*)&hbuf[0][rslot][0];
    const float4* __restrict__ rdpB = (const float4*)&hbuf[1][rslot][0];
    float* __restrict__        wrpA = &hbuf[0][lrow][m];
    float* __restrict__        wrpB = &hbuf[1][lrow][m];

    // Pipelined h fragments: F holds h_t while the body computes h_{t+1}.
    float4 FA0 = rdpA[0], FA1 = rdpA[1], FA2 = rdpA[2], FA3 = rdpA[3], FA4 = rdpA[4];
    float4 FB0 = rdpB[0], FB1 = rdpB[1], FB2 = rdpB[2], FB3 = rdpB[3], FB4 = rdpB[4];

    float4 xqA = *(const float4*)&xrowA[0];   // x[t .. t+3]
    float4 xqB = *(const float4*)&xrowB[0];
    float4 xqA_next, xqB_next;
    float4 obufA = make_float4(0.f, 0.f, 0.f, 0.f);  // out[t-4 .. t-1], comp = idx&3
    float4 obufB = make_float4(0.f, 0.f, 0.f, 0.f);

#define FQ(Q, FF)                                                               \
    {   v2f hA; hA.x = (FF).x; hA.y = (FF).y;                                   \
        v2f hB; hB.x = (FF).z; hB.y = (FF).w;                                   \
        a0 = __builtin_elementwise_fma(whh2[0][2*Q],   hA, a0);                 \
        a1 = __builtin_elementwise_fma(whh2[1][2*Q],   hA, a1);                 \
        a2 = __builtin_elementwise_fma(whh2[2][2*Q],   hA, a2);                 \
        a3 = __builtin_elementwise_fma(whh2[3][2*Q],   hA, a3);                 \
        a0 = __builtin_elementwise_fma(whh2[0][2*Q+1], hB, a0);                 \
        a1 = __builtin_elementwise_fma(whh2[1][2*Q+1], hB, a1);                 \
        a2 = __builtin_elementwise_fma(whh2[2][2*Q+1], hB, a2);                 \
        a3 = __builtin_elementwise_fma(whh2[3][2*Q+1], hB, a3);                 }

// One LSTM step for one stream. Consumes F0..F4 (= h_t), writes h_{t+1} to LDS,
// then immediately issues the reads of h_{t+1} back into F0..F4. The OTHER
// stream's body runs between issue and next use, covering the LDS round-trip.
// All fragment/state names are passed explicitly (no ## pasting).
#define BODY(CS, WRP, RDP, F0, F1, F2, F3, F4, XV, OSLOT)                       \
    {                                                                           \
        const float xv = (XV);                                                  \
        v2f a0, a1, a2, a3;                                                     \
        a0.x = v[0] + xv * u[0]; a0.y = 0.f;                                    \
        a1.x = v[1] + xv * u[1]; a1.y = 0.f;                                    \
        a2.x = v[2] + xv * u[2]; a2.y = 0.f;                                    \
        a3.x = v[3] + xv * u[3]; a3.y = 0.f;                                    \
        FQ(0, F0) FQ(1, F1) FQ(2, F2) FQ(3, F3) FQ(4, F4)                       \
        const float g0 = a0.x + a0.y;                                           \
        const float g1 = a1.x + a1.y;                                           \
        const float g2 = a2.x + a2.y;                                           \
        const float g3 = a3.x + a3.y;                                           \
        OSLOT = g0;                                                             \
        const float ig  = sig_s(g0);                                            \
        const float fg  = sig_s(g1);                                            \
        const float ggs = tanh_2Ls(g2);                                         \
        const float og  = sig_s(g3);                                            \
        CS = fg * CS + ig * ggs;                                                \
        *(WRP) = og * tanh_c(CS);                                               \
        F0 = (RDP)[0]; F1 = (RDP)[1]; F2 = (RDP)[2];                            \
        F3 = (RDP)[3]; F4 = (RDP)[4];                                           \
    }

#define BODYA(XV, OSLOT) BODY(csA, wrpA, rdpA, FA0, FA1, FA2, FA3, FA4, XV, OSLOT)
#define BODYB(XV, OSLOT) BODY(csB, wrpB, rdpB, FB0, FB1, FB2, FB3, FB4, XV, OSLOT)

    for (int t = 0; t < T; t += 4) {
        // prefetch next iteration's x a full 4 steps ahead (clamped on last iter)
        const int tp = (t + 4 < T) ? (t + 4) : t;
        xqA_next = *(const float4*)&xrowA[tp];
        xqB_next = *(const float4*)&xrowB[tp];

        BODYA(xqA.x, obufA.w)                    // step t   -> out[t-1] (comp 3)
        if (t >= 4 && ovalidA) *(float4*)&orowA[t - 4] = obufA;
        BODYB(xqB.x, obufB.w)
        if (t >= 4 && ovalidB) *(float4*)&orowB[t - 4] = obufB;
        BODYA(xqA.y, obufA.x)                    // step t+1 -> out[t]   (comp 0)
        BODYB(xqB.y, obufB.x)
        BODYA(xqA.z, obufA.y)                    // step t+2 -> out[t+1] (comp 1)
        BODYB(xqB.z, obufB.y)
        BODYA(xqA.w, obufA.z)                    // step t+3 -> out[t+2] (comp 2)
        BODYB(xqB.w, obufB.z)

        xqA = xqA_next;
        xqB = xqB_next;
    }

    // epilogue: out[T-1] = b2 + W2 @ h_T ; h_T is in F (reads issued by last body)
#define EPILOG(F0, F1, F2, F3, F4, OBUF, OVALID, OROW)                          \
    {                                                                           \
        float o = v[0];                                                         \
        o += whh2[0][0].x * (F0).x + whh2[0][0].y * (F0).y                      \
           + whh2[0][1].x * (F0).z + whh2[0][1].y * (F0).w;                     \
        o += whh2[0][2].x * (F1).x + whh2[0][2].y * (F1).y                      \
           + whh2[0][3].x * (F1).z + whh2[0][3].y * (F1).w;                     \
        o += whh2[0][4].x * (F2).x + whh2[0][4].y * (F2).y                      \
           + whh2[0][5].x * (F2).z + whh2[0][5].y * (F2).w;                     \
        o += whh2[0][6].x * (F3).x + whh2[0][6].y * (F3).y                      \
           + whh2[0][7].x * (F3).z + whh2[0][7].y * (F3).w;                     \
        o += whh2[0][8].x * (F4).x + whh2[0][8].y * (F4).y                      \
           + whh2[0][9].x * (F4).z + whh2[0][9].y * (F4).w;                     \
        (OBUF).w = o;                                                           \
        if (OVALID) *(float4*)&(OROW)[T - 4] = (OBUF);                          \
    }

    EPILOG(FA0, FA1, FA2, FA3, FA4, obufA, ovalidA, orowA)
    EPILOG(FB0, FB1, FB2, FB3, FB4, obufB, ovalidB, orowB)
#undef EPILOG
#undef BODYA
#undef BODYB
#undef BODY
#undef FQ
}

extern "C" void kernel_launch(void* const* d_in, const int* in_sizes, int n_in,
                              void* d_out, int out_size, void* d_ws, size_t ws_size,
                              hipStream_t stream) {
    (void)n_in; (void)d_ws; (void)ws_size; (void)out_size;
    const float* x    = (const float*)d_in[0];
    const float* W1   = (const float*)d_in[1];
    const float* b1   = (const float*)d_in[2];
    const float* W_ih = (const float*)d_in[3];
    const float* W_hh = (const float*)d_in[4];
    const float* b_ih = (const float*)d_in[5];
    const float* b_hh = (const float*)d_in[6];
    const float* W2   = (const float*)d_in[7];
    const float* b2   = (const float*)d_in[8];
    float* out        = (float*)d_out;

    const int B = 8192;
    const int T = in_sizes[0] / B;  // 2048 (divisible by 4)
    const int grid = (B + ROWS_PER_BLOCK - 1) / ROWS_PER_BLOCK;  // 1366 single-wave blocks

    lstm_wave<<<grid, NTHREADS, 0, stream>>>(x, W1, b1, W_ih, W_hh, b_ih, b_hh, W2, b2, out, B, T);
}

// Round 5
// 1425.802 us; speedup vs baseline: 1.0141x; 1.0141x over previous
//
#include <hip/hip_runtime.h>

// Net_4544075399853: x->20 linear, LSTMCell(20,20), 20->1 linear; B=8192, T=2048, fp32.
// R10b: identical to R10 (previous round was an infra failure, not a kernel
// failure). h-exchange via ds_bpermute (register crossbar) instead of LDS
// write+read.
//  - R8's measured stall: per-step wall 1330cy, own-issue 380cy -> ~300-500cy
//    exposed on the ds_write -> 5x ds_read_b128 round-trip (in-order LDS pipe,
//    same-address dependency, 2.67-wave DS contention). Covered only by a-init.
//  - ds_bpermute_b32 pulls each row-group's 20 h values lane-to-lane with NO
//    memory write, no write->read serialization, no LDS allocation. 20 pulls
//    replace 1 write + 5 reads (+14 issue slots vs ~400cy stall removed).
//  - Keeps R8's grid: 2731 single-wave blocks (2.67 waves/SIMD) = best measured
//    load balance (R9b showed 1366-wave grids cap at the 2-wave-SIMD floor).
//  - Math bit-identical to R8 (exchange is a bit-copy): exp2-domain activations,
//    x as float4/4 steps prefetched 1 iter ahead, packed float4 out stores.
//  - Lanes 0-59: 3 rows x 20 units; whh = 40 float2 (80 VGPRs) pinned via asm.
//  - Lanes 60-62: output lanes (whh row0=W2, v[0]=b2) -> their g0 IS out[t-1].
//  - Lane 63: pulls wrapped/garbage sources -> garbage in its private state
//    only; it never stores (ovalid false), addresses clamped.

#define HID 20
#define ROWS_PER_WAVE 3
#define NTHREADS 64
#define L2E 1.4426950408889634f

typedef float v2f __attribute__((ext_vector_type(2)));

__device__ __forceinline__ float exp2_hw(float v) { return __builtin_amdgcn_exp2f(v); }
__device__ __forceinline__ float rcp_hw(float v)  { return __builtin_amdgcn_rcpf(v); }

// gs = log2e * g   -> sigmoid(g)
__device__ __forceinline__ float sig_s(float gs) {
    return rcp_hw(1.0f + exp2_hw(-gs));
}
// gs2 = 2*log2e*g  -> 2*log2e * tanh(g)  (pre-scaled for the c update)
__device__ __forceinline__ float tanh_2Ls(float gs2) {
    return (2.0f * L2E) - (4.0f * L2E) * rcp_hw(1.0f + exp2_hw(gs2));
}
// cs = 2*log2e*c   -> tanh(c)
__device__ __forceinline__ float tanh_c(float cs) {
    return 1.0f - 2.0f * rcp_hw(1.0f + exp2_hw(cs));
}

__global__ __attribute__((amdgpu_flat_work_group_size(NTHREADS, NTHREADS),
                          amdgpu_waves_per_eu(3, 3)))
void lstm_wave(
        const float* __restrict__ x,     // [B, T]
        const float* __restrict__ W1,    // [20]
        const float* __restrict__ b1,    // [20]
        const float* __restrict__ W_ih,  // [80, 20]
        const float* __restrict__ W_hh,  // [80, 20]
        const float* __restrict__ b_ih,  // [80]
        const float* __restrict__ b_hh,  // [80]
        const float* __restrict__ W2,    // [20]
        const float* __restrict__ b2,    // [1]
        float* __restrict__ out,         // [B, T]
        const int B, const int T)
{
    const int lane = threadIdx.x;
    const int lrow = lane / HID;          // 0..3 (3 = special lanes 60-63)
    const int m    = lane % HID;          // 0..19 (0..3 for lanes 60-63)
    const bool outlane = (lrow == 3) && (m < ROWS_PER_WAVE);   // lanes 60,61,62
    const int rslot = (lrow == 3) ? m : lrow;  // lane-group this lane PULLS from
    const long rowbase = (long)blockIdx.x * ROWS_PER_WAVE;
    const long row = rowbase + ((lrow == 3) ? (long)((m < 3) ? m : 0) : (long)lrow);
    const long arow = (row < B) ? row : (B - 1);     // safe address for OOB/aux lanes
    const bool ovalid = outlane && (row < B);

    // byte index of source lane-group base for ds_bpermute (lane k of group = +4k)
    const int base4 = rslot * (HID * 4);

    // ---- phase 1: u, v (NO weight arrays live here; W1/b1 are uniform loads) ----
    float u[4], v[4];
    if (lrow < 3) {
#pragma unroll
        for (int g = 0; g < 4; ++g) {
            const int j = g * HID + m;            // torch gate order i,f,g,o
            const float s = (g == 2) ? (2.0f * L2E) : L2E;
            float uu = 0.f, vv = 0.f;
#pragma unroll
            for (int k = 0; k < HID; ++k) {
                const float wi = W_ih[j * HID + k];
                uu += wi * W1[k];
                vv += wi * b1[k];
            }
            u[g] = s * uu;
            v[g] = s * (vv + b_ih[j] + b_hh[j]);
        }
    } else {
#pragma unroll
        for (int g = 0; g < 4; ++g) { u[g] = 0.f; v[g] = 0.f; }
        v[0] = b2[0];
    }

    // ---- phase 2: whh as 40 float2 pairs (scaled), loaded with low live-set ----
    v2f whh2[4][HID / 2];
    if (lrow < 3) {
#pragma unroll
        for (int g = 0; g < 4; ++g) {
            const int j = g * HID + m;
            const float s = (g == 2) ? (2.0f * L2E) : L2E;
#pragma unroll
            for (int kk = 0; kk < HID / 2; ++kk) {
                v2f w;
                w.x = s * W_hh[j * HID + 2 * kk];
                w.y = s * W_hh[j * HID + 2 * kk + 1];
                whh2[g][kk] = w;
            }
        }
    } else {
#pragma unroll
        for (int kk = 0; kk < HID / 2; ++kk) {
            v2f w; w.x = W2[2 * kk]; w.y = W2[2 * kk + 1];
            whh2[0][kk] = w;
            whh2[1][kk] = (v2f)(0.f);
            whh2[2][kk] = (v2f)(0.f);
            whh2[3][kk] = (v2f)(0.f);
        }
    }

    // Opaque defs: prevent remat of the weight loads into the loop.
#pragma unroll
    for (int g = 0; g < 4; ++g)
#pragma unroll
        for (int kk = 0; kk < HID / 2; ++kk)
            asm volatile("" : "+v"(whh2[g][kk]));

    float cs = 0.f;   // c in 2*log2e-scaled domain

    const float* __restrict__ xrow = x   + arow * T;
    float* __restrict__       orow = out + arow * T;

    // h_t fragments, one full row per lane, as 10 packed pairs (pk_fma operands).
    v2f Fp[HID / 2];
#pragma unroll
    for (int q = 0; q < HID / 2; ++q) Fp[q] = (v2f)(0.f);   // h_0 = 0

    float4 xq = *(const float4*)&xrow[0];   // x[t .. t+3]
    float4 xq_next;
    float4 obuf = make_float4(0.f, 0.f, 0.f, 0.f);  // out[t-4 .. t-1], comp = idx&3

// One LSTM step. Consumes Fp (= h_t), computes h_{t+1} in a VGPR, then pulls
// the row-group's 20 new h values via ds_bpermute (register crossbar — no LDS
// memory, no write->read round trip).
#define BODY(XV, OSLOT)                                                         \
    {                                                                           \
        const float xv = (XV);                                                  \
        v2f a0, a1, a2, a3;                                                     \
        a0.x = v[0] + xv * u[0]; a0.y = 0.f;                                    \
        a1.x = v[1] + xv * u[1]; a1.y = 0.f;                                    \
        a2.x = v[2] + xv * u[2]; a2.y = 0.f;                                    \
        a3.x = v[3] + xv * u[3]; a3.y = 0.f;                                    \
        _Pragma("unroll")                                                       \
        for (int q = 0; q < HID / 2; ++q) {                                     \
            a0 = __builtin_elementwise_fma(whh2[0][q], Fp[q], a0);              \
            a1 = __builtin_elementwise_fma(whh2[1][q], Fp[q], a1);              \
            a2 = __builtin_elementwise_fma(whh2[2][q], Fp[q], a2);              \
            a3 = __builtin_elementwise_fma(whh2[3][q], Fp[q], a3);              \
        }                                                                       \
        const float g0 = a0.x + a0.y;                                           \
        const float g1 = a1.x + a1.y;                                           \
        const float g2 = a2.x + a2.y;                                           \
        const float g3 = a3.x + a3.y;                                           \
        OSLOT = g0;                                                             \
        const float ig  = sig_s(g0);                                            \
        const float fg  = sig_s(g1);                                            \
        const float ggs = tanh_2Ls(g2);                                         \
        const float og  = sig_s(g3);                                            \
        cs = fg * cs + ig * ggs;                                                \
        const float hnew = og * tanh_c(cs);                                     \
        const int hb = __float_as_int(hnew);                                    \
        _Pragma("unroll")                                                       \
        for (int q = 0; q < HID / 2; ++q) {                                     \
            Fp[q].x = __int_as_float(                                           \
                __builtin_amdgcn_ds_bpermute(base4 + 8 * q,     hb));           \
            Fp[q].y = __int_as_float(                                           \
                __builtin_amdgcn_ds_bpermute(base4 + 8 * q + 4, hb));           \
        }                                                                       \
    }

    for (int t = 0; t < T; t += 4) {
        // prefetch next iteration's x a full 4 steps ahead (clamped on last iter)
        const int tp = (t + 4 < T) ? (t + 4) : t;
        xq_next = *(const float4*)&xrow[tp];

        BODY(xq.x, obuf.w)                       // step t   -> out[t-1] (comp 3)
        if (t >= 4 && ovalid) *(float4*)&orow[t - 4] = obuf;   // out[t-4..t-1]
        BODY(xq.y, obuf.x)                       // step t+1 -> out[t]   (comp 0)
        BODY(xq.z, obuf.y)                       // step t+2 -> out[t+1] (comp 1)
        BODY(xq.w, obuf.z)                       // step t+3 -> out[t+2] (com 2)

        xq = xq_next;
    }

    // epilogue: out[T-1] = b2 + W2 @ h_T ; h_T is in Fp (pulled by last body)
    {
        float o = v[0];
#pragma unroll
        for (int q = 0; q < HID / 2; ++q) {
            o += whh2[0][q].x * Fp[q].x + whh2[0][q].y * Fp[q].y;
        }
        obuf.w = o;                                   // out[T-1] (comp 3)
        if (ovalid) *(float4*)&orow[T - 4] = obuf;    // out[T-4..T-1]
    }
#undef BODY
}

extern "C" void kernel_launch(void* const* d_in, const int* in_sizes, int n_in,
                              void* d_out, int out_size, void* d_ws, size_t ws_size,
                              hipStream_t stream) {
    (void)n_in; (void)d_ws; (void)ws_size; (void)out_size;
    const float* x    = (const float*)d_in[0];
    const float* W1   = (const float*)d_in[1];
    const float* b1   = (const float*)d_in[2];
    const float* W_ih = (const float*)d_in[3];
    const float* W_hh = (const float*)d_in[4];
    const float* b_ih = (const float*)d_in[5];
    const float* b_hh = (const float*)d_in[6];
    const float* W2   = (const float*)d_in[7];
    const float* b2   = (const float*)d_in[8];
    float* out        = (float*)d_out;

    const int B = 8192;
    const int T = in_sizes[0] / B;  // 2048 (divisible by 4)
    const int grid = (B + ROWS_PER_WAVE - 1) / ROWS_PER_WAVE;  // 2731 single-wave blocks

    lstm_wave<<<grid, NTHREADS, 0, stream>>>(x, W1, b1, W_ih, W_hh, b_ih, b_hh, W2, b2, out, B, T);
}

// Round 6
// 1100.641 us; speedup vs baseline: 1.3136x; 1.2954x over previous
//
#include <hip/hip_runtime.h>

// Net_4544075399853: x->20 linear, LSTMCell(20,20), 20->1 linear; B=8192, T=2048, fp32.
// R11: revert to R8 structure (best: 1135us rocprof) + phase-desync + a-init trim.
//  - R10b (bpermute exchange) REGRESSED (1553us): 20 wave64 ds_bpermute/step
//    saturate the per-CU LDS pipe (~10.7 waves/CU sharing it). Keep R8's
//    1 ds_write + 5 ds_read_b128 exchange.
//  - R8 residual: per-wave issue 324us, 3-wave-SIMD floor 972us, measured 1135
//    -> ~190cy/step stall where NO wave issues. Co-resident waves (blockIdx
//    b, b+1024, b+2048 land on the same SIMD: 8 XCD x 32 CU x 4 SIMD = 1024)
//    are dispatched together and run identical per-step code -> they hit the
//    ds_write->ds_read wait window simultaneously (phase-locked stall; wave
//    TLP can't cover it). Fix: one-time s_sleep stagger of ~1/3 step-wall per
//    co-residency slot so the windows interleave.
//  - a-init via packed {u,v}x{xv,1} pk_fma: 4 pk_fma + 1 mov replaces
//    4 fma + 4 mov (-3 insts/step). g = a.x+a.y now adds v via the .y chain
//    (benign reassociation).
//  - Barrier-free single-buffer LDS h-exchange (single-wave workgroup, DS ops
//    wave-program-ordered). x as float4/4 steps prefetched 1 iter ahead;
//    packed float4 out stores. exp2-domain activations.
//  - Lanes 0-59: 3 rows x 20 units; whh = 40 float2 (80 regs) pinned via asm.
//  - Lanes 60-62: output lanes (whh row0=W2, uv0={0,b2}) -> their g0 IS out[t-1].

#define HID 20
#define ROWS_PER_WAVE 3
#define NTHREADS 64
#define L2E 1.4426950408889634f

typedef float v2f __attribute__((ext_vector_type(2)));

__device__ __forceinline__ float exp2_hw(float v) { return __builtin_amdgcn_exp2f(v); }
__device__ __forceinline__ float rcp_hw(float v)  { return __builtin_amdgcn_rcpf(v); }

// gs = log2e * g   -> sigmoid(g)
__device__ __forceinline__ float sig_s(float gs) {
    return rcp_hw(1.0f + exp2_hw(-gs));
}
// gs2 = 2*log2e*g  -> 2*log2e * tanh(g)  (pre-scaled for the c update)
__device__ __forceinline__ float tanh_2Ls(float gs2) {
    return (2.0f * L2E) - (4.0f * L2E) * rcp_hw(1.0f + exp2_hw(gs2));
}
// cs = 2*log2e*c   -> tanh(c)
__device__ __forceinline__ float tanh_c(float cs) {
    return 1.0f - 2.0f * rcp_hw(1.0f + exp2_hw(cs));
}

__global__ __attribute__((amdgpu_flat_work_group_size(NTHREADS, NTHREADS),
                          amdgpu_waves_per_eu(3, 3)))
void lstm_wave(
        const float* __restrict__ x,     // [B, T]
        const float* __restrict__ W1,    // [20]
        const float* __restrict__ b1,    // [20]
        const float* __restrict__ W_ih,  // [80, 20]
        const float* __restrict__ W_hh,  // [80, 20]
        const float* __restrict__ b_ih,  // [80]
        const float* __restrict__ b_hh,  // [80]
        const float* __restrict__ W2,    // [20]
        const float* __restrict__ b2,    // [1]
        float* __restrict__ out,         // [B, T]
        const int B, const int T)
{
    const int lane = threadIdx.x;
    const int lrow = lane / HID;          // 0..3 (3 = special lanes 60-63)
    const int m    = lane % HID;          // 0..19 (0..3 for lanes 60-63)
    const bool outlane = (lrow == 3) && (m < ROWS_PER_WAVE);   // lanes 60,61,62
    const int rslot = (lrow == 3) ? m : lrow;  // LDS row slot this lane READS
    const long rowbase = (long)blockIdx.x * ROWS_PER_WAVE;
    const long row = rowbase + ((lrow == 3) ? (long)((m < 3) ? m : 0) : (long)lrow);
    const long arow = (row < B) ? row : (B - 1);     // safe address for OOB/aux lanes
    const bool ovalid = outlane && (row < B);

    // single buffer: [4 row slots (slot 3 = trash)][20 units]
    __shared__ __align__(16) float hbuf[ROWS_PER_WAVE + 1][HID];

    // ---- phase 1: u, v (NO weight arrays live here; W1/b1 are uniform loads) ----
    float u[4], v[4];
    if (lrow < 3) {
#pragma unroll
        for (int g = 0; g < 4; ++g) {
            const int j = g * HID + m;            // torch gate order i,f,g,o
            const float s = (g == 2) ? (2.0f * L2E) : L2E;
            float uu = 0.f, vv = 0.f;
#pragma unroll
            for (int k = 0; k < HID; ++k) {
                const float wi = W_ih[j * HID + k];
                uu += wi * W1[k];
                vv += wi * b1[k];
            }
            u[g] = s * uu;
            v[g] = s * (vv + b_ih[j] + b_hh[j]);
        }
    } else {
#pragma unroll
        for (int g = 0; g < 4; ++g) { u[g] = 0.f; v[g] = 0.f; }
        v[0] = b2[0];
    }
    const float v0e = v[0];               // epilogue bias (b2 for outlanes)

    // packed {u, v} per gate: a-init becomes pk_fma(uv[g], {xv, 1}, 0)
    v2f uv[4];
#pragma unroll
    for (int g = 0; g < 4; ++g) { uv[g].x = u[g]; uv[g].y = v[g]; }

    // ---- phase 2: whh as 40 float2 pairs (scaled), loaded with low live-set ----
    v2f whh2[4][HID / 2];
    if (lrow < 3) {
#pragma unroll
        for (int g = 0; g < 4; ++g) {
            const int j = g * HID + m;
            const float s = (g == 2) ? (2.0f * L2E) : L2E;
#pragma unroll
            for (int kk = 0; kk < HID / 2; ++kk) {
                v2f w;
                w.x = s * W_hh[j * HID + 2 * kk];
                w.y = s * W_hh[j * HID + 2 * kk + 1];
                whh2[g][kk] = w;
            }
        }
    } else {
#pragma unroll
        for (int kk = 0; kk < HID / 2; ++kk) {
            v2f w; w.x = W2[2 * kk]; w.y = W2[2 * kk + 1];
            whh2[0][kk] = w;
            whh2[1][kk] = (v2f)(0.f);
            whh2[2][kk] = (v2f)(0.f);
            whh2[3][kk] = (v2f)(0.f);
        }
    }

    // Opaque defs: prevent remat of the weight loads into the loop.
#pragma unroll
    for (int g = 0; g < 4; ++g)
#pragma unroll
        for (int kk = 0; kk < HID / 2; ++kk)
            asm volatile("" : "+v"(whh2[g][kk]));

    float cs = 0.f;   // c in 2*log2e-scaled domain
    hbuf[lrow][m] = 0.f;
    if (lane < HID) hbuf[3][lane] = 0.f;   // fully init trash row (NaN hygiene)
    // NOTE: no __syncthreads anywhere — single-wave workgroup, DS ops are
    // executed in wave program order by the LDS pipe.

    // ---- phase desync: co-resident waves are blockIdx b, b+1024, b+2048 ----
    // Offset each co-residency slot by ~1/3 of a step-wall so the per-step
    // LDS-wait windows of the 3 waves on a SIMD interleave instead of
    // overlapping (phase-locked stall measured at ~190cy/step in R8).
    {
        const unsigned slot = (unsigned)blockIdx.x >> 10;   // 0,1,2
        if (slot == 1) __builtin_amdgcn_s_sleep(5);         // ~320 cy
        else if (slot == 2) __builtin_amdgcn_s_sleep(10);   // ~640 cy
    }

    const float* __restrict__ xrow = x   + arow * T;
    float* __restrict__       orow = out + arow * T;

    const float4* __restrict__ rdp = (const float4*)&hbuf[rslot][0];
    float* __restrict__        wrp = &hbuf[lrow][m];

    // Pipelined h fragments: F holds h_t while the body computes h_{t+1}.
    float4 F0 = rdp[0], F1 = rdp[1], F2 = rdp[2], F3 = rdp[3], F4 = rdp[4];

    float4 xq = *(const float4*)&xrow[0];   // x[t .. t+3]
    float4 xq_next;
    float4 obuf = make_float4(0.f, 0.f, 0.f, 0.f);  // out[t-4 .. t-1], comp = idx&3
    const v2f zero2 = (v2f)(0.f);

#define FQ(Q, FF)                                                               \
    {   v2f hA; hA.x = (FF).x; hA.y = (FF).y;                                   \
        v2f hB; hB.x = (FF).z; hB.y = (FF).w;                                   \
        a0 = __builtin_elementwise_fma(whh2[0][2*Q],   hA, a0);                 \
        a1 = __builtin_elementwise_fma(whh2[1][2*Q],   hA, a1);                 \
        a2 = __builtin_elementwise_fma(whh2[2][2*Q],   hA, a2);                 \
        a3 = __builtin_elementwise_fma(whh2[3][2*Q],   hA, a3);                 \
        a0 = __builtin_elementwise_fma(whh2[0][2*Q+1], hB, a0);                 \
        a1 = __builtin_elementwise_fma(whh2[1][2*Q+1], hB, a1);                 \
        a2 = __builtin_elementwise_fma(whh2[2][2*Q+1], hB, a2);                 \
        a3 = __builtin_elementwise_fma(whh2[3][2*Q+1], hB, a3);                 }

// One LSTM step. Consumes F (= h_t), writes h_{t+1} to LDS, then immediately
// issues the reads of h_{t+1} back into F for the next step.
#define BODY(XV, OSLOT)                                                         \
    {                                                                           \
        v2f xw; xw.x = (XV); xw.y = 1.0f;                                       \
        v2f a0 = __builtin_elementwise_fma(uv[0], xw, zero2);                   \
        v2f a1 = __builtin_elementwise_fma(uv[1], xw, zero2);                   \
        v2f a2 = __builtin_elementwise_fma(uv[2], xw, zero2);                   \
        v2f a3 = __builtin_elementwise_fma(uv[3], xw, zero2);                   \
        FQ(0, F0) FQ(1, F1) FQ(2, F2) FQ(3, F3) FQ(4, F4)                       \
        const float g0 = a0.x + a0.y;                                           \
        const float g1 = a1.x + a1.y;                                           \
        const float g2 = a2.x + a2.y;                                           \
        const float g3 = a3.x + a3.y;                                           \
        OSLOT = g0;                                                             \
        const float ig  = sig_s(g0);                                            \
        const float fg  = sig_s(g1);                                            \
        const float ggs = tanh_2Ls(g2);                                         \
        const float og  = sig_s(g3);                                            \
        cs = fg * cs + ig * ggs;                                                \
        *wrp = og * tanh_c(cs);                                                 \
        F0 = rdp[0]; F1 = rdp[1]; F2 = rdp[2]; F3 = rdp[3]; F4 = rdp[4];        \
    }

    for (int t = 0; t < T; t += 4) {
        // prefetch next iteration's x a full 4 steps ahead (clamped on last iter)
        const int tp = (t + 4 < T) ? (t + 4) : t;
        xq_next = *(const float4*)&xrow[tp];

        BODY(xq.x, obuf.w)                       // step t   -> out[t-1] (comp 3)
        if (t >= 4 && ovalid) *(float4*)&orow[t - 4] = obuf;   // out[t-4..t-1]
        BODY(xq.y, obuf.x)                       // step t+1 -> out[t]   (comp 0)
        BODY(xq.z, obuf.y)                       // step t+2 -> out[t+1] (comp 1)
        BODY(xq.w, obuf.z)                       // step t+3 -> out[t+2] (comp 2)

        xq = xq_next;
    }

    // epilogue: out[T-1] = b2 + W2 @ h_T ; h_T is in F (reads issued by last body)
    {
        float o = v0e;
        o += whh2[0][0].x * F0.x + whh2[0][0].y * F0.y
           + whh2[0][1].x * F0.z + whh2[0][1].y * F0.w;
        o += whh2[0][2].x * F1.x + whh2[0][2].y * F1.y
           + whh2[0][3].x * F1.z + whh2[0][3].y * F1.w;
        o += whh2[0][4].x * F2.x + whh2[0][4].y * F2.y
           + whh2[0][5].x * F2.z + whh2[0][5].y * F2.w;
        o += whh2[0][6].x * F3.x + whh2[0][6].y * F3.y
           + whh2[0][7].x * F3.z + whh2[0][7].y * F3.w;
        o += whh2[0][8].x * F4.x + whh2[0][8].y * F4.y
           + whh2[0][9].x * F4.z + whh2[0][9].y * F4.w;
        obuf.w = o;                                   // out[T-1] (comp 3)
        if (ovalid) *(float4*)&orow[T - 4] = obuf;    // out[T-4..T-1]
    }
#undef BODY
#undef FQ
}

extern "C" void kernel_launch(void* const* d_in, const int* in_sizes, int n_in,
                              void* d_out, int out_size, void* d_ws, size_t ws_size,
                              hipStream_t stream) {
    (void)n_in; (void)d_ws; (void)ws_size; (void)out_size;
    const float* x    = (const float*)d_in[0];
    const float* W1   = (const float*)d_in[1];
    const float* b1   = (const float*)d_in[2];
    const float* W_ih = (const float*)d_in[3];
    const float* W_hh = (const float*)d_in[4];
    const float* b_ih = (const float*)d_in[5];
    const float* b_hh = (const float*)d_in[6];
    const float* W2   = (const float*)d_in[7];
    const float* b2   = (const float*)d_in[8];
    float* out        = (float*)d_out;

    const int B = 8192;
    const int T = in_sizes[0] / B;  // 2048 (divisible by 4)
    const int grid = (B + ROWS_PER_WAVE - 1) / ROWS_PER_WAVE;  // 2731 single-wave blocks

    lstm_wave<<<grid, NTHREADS, 0, stream>>>(x, W1, b1, W_ih, W_hh, b_ih, b_hh, W2, b2, out, B, T);
}